// Round 8
// baseline (427.670 us; speedup 1.0000x reference)
//
#include <hip/hip_runtime.h>
#include <hip/hip_bf16.h>

// ---------------------------------------------------------------------------
// ROLAND-style GNN forward. Round 7: BM=64 GEMM tiles (2-4x more blocks ->
// TLP hides HBM latency) + all-bf16 intermediate chain (h2, agg1, agg2 bf16;
// gathers emit packed bf16; concat-GEMMs take bf16 A1 + fp32 A2).
// GEMMs: 2-pass split precision (bf16 act, hi/lo bf16 weights), double-buffered.
// Bucketed CSR build; bf16 CSR gather with 8-deep ILP.
// ---------------------------------------------------------------------------

typedef unsigned short ushort_t;
typedef __attribute__((ext_vector_type(8))) short s8v;   // 8 bf16 (4 VGPRs)
typedef __attribute__((ext_vector_type(4))) float f4;    // MFMA accumulator

#define BSHIFT 8                       // nodes per bucket = 256 (N<=65536)

// split fp32 into two bf16 (RNE): v ~= hi + lo  (weights only)
__device__ __forceinline__ void bsplit(float v, ushort_t& hi, ushort_t& lo) {
    unsigned u = __float_as_uint(v);
    unsigned rh = u + 0x7FFFu + ((u >> 16) & 1u);
    hi = (ushort_t)(rh >> 16);
    float fh = __uint_as_float((unsigned)hi << 16);
    float d = v - fh;
    unsigned u2 = __float_as_uint(d);
    unsigned rl = u2 + 0x7FFFu + ((u2 >> 16) & 1u);
    lo = (ushort_t)(rl >> 16);
}

__device__ __forceinline__ ushort_t f2bf(float v) {
    unsigned u = __float_as_uint(v);
    return (ushort_t)((u + 0x7FFFu + ((u >> 16) & 1u)) >> 16);
}

// ---------------- MFMA GEMM (2-pass, double-buffered, BM=64) ----------------
// C[M,Nout] = epilogue( A[M,K1] (++ A2[M,K2]) @ W[K,Nout] )
// A staged as bf16 in LDS (chunk-XOR swizzle); W pre-split hi/lo [Nout][KW].
// 256 thr = 4 waves (2x2): wave tile 32 x (NT*16). BM=64, BN=NT*32.
// ABF: A1 is pre-quantized bf16. OUTMODE: 0 = fp32, 2 = bf16.
template <int NT, bool RELU, bool SCALE, bool DUAL, bool ABF, int OUTMODE>
__global__ __launch_bounds__(256) void gemm_mfma(
    const float* __restrict__ A1f, const ushort_t* __restrict__ A1h, int K1,
    const float* __restrict__ A2f, int K2,
    const ushort_t* __restrict__ Wth, const ushort_t* __restrict__ Wtl,
    const float* __restrict__ bias, const float* __restrict__ rowscale,
    float* __restrict__ Cf, ushort_t* __restrict__ Ch,
    int M, int Nout)
{
    __shared__ ushort_t Abuf[2][64 * 64];
    const int tid  = threadIdx.x;
    const int lane = tid & 63;
    const int w    = tid >> 6;
    const int wr   = w >> 1, wc = w & 1;
    const int bm   = blockIdx.y * 64;
    const int bn   = blockIdx.x * (NT * 32);
    const int KW   = K1 + (DUAL ? K2 : 0);
    const int nt   = KW >> 6;

    f4 acc[2][NT];
    const f4 zero = {0.f, 0.f, 0.f, 0.f};
#pragma unroll
    for (int mi = 0; mi < 2; ++mi)
#pragma unroll
        for (int ni = 0; ni < NT; ++ni) acc[mi][ni] = zero;

    const int sr = tid >> 2;                 // staging row 0..63
    const int sh = tid & 3;                  // chunk pair index 0..3
    const int gr = min(bm + sr, M - 1);      // clamped global row

    f4  pr[4];     // fp32 prefetch
    s8v pu[2];     // bf16 prefetch
    bool pf2 = false;

    auto loadT = [&](int kt) {
        const bool ph2 = DUAL && (kt >= K1);
        pf2 = ph2;
        if (ABF && !ph2) {
#pragma unroll
            for (int j = 0; j < 2; ++j)
                pu[j] = *(const s8v*)&A1h[(size_t)gr * K1 + kt + (sh * 2 + j) * 8];
        } else {
            const float* Af; int kb, Ks;
            if (ph2) { Af = A2f; kb = kt - K1; Ks = K2; }
            else     { Af = A1f; kb = kt;      Ks = K1; }
#pragma unroll
            for (int j = 0; j < 2; ++j) {
                const float* sp = &Af[(size_t)gr * Ks + kb + (sh * 2 + j) * 8];
                pr[2 * j]     = *(const f4*)sp;
                pr[2 * j + 1] = *(const f4*)(sp + 4);
            }
        }
    };
    auto storeT = [&](ushort_t* buf) {
#pragma unroll
        for (int j = 0; j < 2; ++j) {
            const int c = sh * 2 + j;
            const int p = c ^ (sr & 7);            // bank swizzle
            ushort_t hb[8];
            if (ABF && !pf2) {
                *(s8v*)hb = pu[j];
            } else {
                f4 v0 = pr[2 * j], v1 = pr[2 * j + 1];
                hb[0] = f2bf(v0.x); hb[1] = f2bf(v0.y);
                hb[2] = f2bf(v0.z); hb[3] = f2bf(v0.w);
                hb[4] = f2bf(v1.x); hb[5] = f2bf(v1.y);
                hb[6] = f2bf(v1.z); hb[7] = f2bf(v1.w);
            }
            *(s8v*)&buf[sr * 64 + p * 8] = *(const s8v*)hb;
        }
    };

    loadT(0);
    storeT(Abuf[0]);
    __syncthreads();
    int cur = 0;

    for (int t = 0; t < nt; ++t) {
        if (t + 1 < nt) loadT((t + 1) * 64);     // issue next-tile global loads
        const int kt = t * 64;
#pragma unroll
        for (int ks = 0; ks < 2; ++ks) {
            s8v bh[NT], bl[NT];
#pragma unroll
            for (int ni = 0; ni < NT; ++ni) {
                const int n = bn + wc * (NT * 16) + ni * 16 + (lane & 15);
                const size_t off = (size_t)n * KW + kt + ks * 32 + (lane >> 4) * 8;
                bh[ni] = *(const s8v*)&Wth[off];
                bl[ni] = *(const s8v*)&Wtl[off];
            }
#pragma unroll
            for (int mi = 0; mi < 2; ++mi) {
                const int row = wr * 32 + mi * 16 + (lane & 15);
                const int c = ks * 4 + (lane >> 4);
                const int p = c ^ (row & 7);
                const s8v ah = *(const s8v*)&Abuf[cur][row * 64 + p * 8];
#pragma unroll
                for (int ni = 0; ni < NT; ++ni) {
                    acc[mi][ni] = __builtin_amdgcn_mfma_f32_16x16x32_bf16(ah, bh[ni], acc[mi][ni], 0, 0, 0);
                    acc[mi][ni] = __builtin_amdgcn_mfma_f32_16x16x32_bf16(ah, bl[ni], acc[mi][ni], 0, 0, 0);
                }
            }
        }
        if (t + 1 < nt) storeT(Abuf[cur ^ 1]);   // vmcnt waits land here, after MFMA
        __syncthreads();
        cur ^= 1;
    }

    // ---- epilogue: C/D layout col=lane&15, row=(lane>>4)*4+reg ----
#pragma unroll
    for (int mi = 0; mi < 2; ++mi) {
#pragma unroll
        for (int reg = 0; reg < 4; ++reg) {
            const int row = bm + wr * 32 + mi * 16 + (lane >> 4) * 4 + reg;
            if (row >= M) continue;
            const float rs = SCALE ? rowscale[row] : 1.f;
#pragma unroll
            for (int ni = 0; ni < NT; ++ni) {
                const int col = bn + wc * (NT * 16) + ni * 16 + (lane & 15);
                float v = acc[mi][ni][reg];
                if (SCALE) v *= rs;
                if (bias) v += bias[col];
                if (RELU) v = fmaxf(v, 0.f);
                if constexpr (OUTMODE == 2) {
                    Ch[(size_t)row * Nout + col] = f2bf(v);
                } else {
                    Cf[(size_t)row * Nout + col] = v;
                }
            }
        }
    }
}

// ---------------- weight transpose + split ---------------------------------
struct WDesc { const float* W; ushort_t* h; ushort_t* l; int K; int No; };
struct WAll { WDesc d[6]; };

__global__ void wtcvt_kernel(WAll wa) {
    WDesc d = wa.d[blockIdx.y];
    int e = blockIdx.x * blockDim.x + threadIdx.x;
    if (e >= d.K * d.No) return;
    int k = e / d.No, n = e - k * d.No;
    ushort_t h, l;
    bsplit(d.W[e], h, l);
    d.h[(size_t)n * d.K + k] = h;
    d.l[(size_t)n * d.K + k] = l;
}

// ---------------- bucketed CSR build ----------------------------------------
__global__ __launch_bounds__(256) void bcount_kernel(const int* __restrict__ dst,
                                                     int* __restrict__ bcount, int E, int NB) {
    __shared__ int cnt[256];
    const int t = threadIdx.x;
    if (t < NB) cnt[t] = 0;
    __syncthreads();
    for (int e = blockIdx.x * 256 + t; e < E; e += gridDim.x * 256)
        atomicAdd(&cnt[dst[e] >> BSHIFT], 1);
    __syncthreads();
    if (t < NB && cnt[t]) atomicAdd(&bcount[t], cnt[t]);
}

__global__ __launch_bounds__(256) void bscan_kernel(const int* __restrict__ bcount,
                                                    int* __restrict__ bbase,
                                                    int* __restrict__ bcursor, int NB, int E) {
    __shared__ int s[256];
    const int t = threadIdx.x;
    s[t] = (t < NB) ? bcount[t] : 0;
    __syncthreads();
    for (int off = 1; off < 256; off <<= 1) {
        int v = (t >= off) ? s[t - off] : 0;
        __syncthreads();
        s[t] += v;
        __syncthreads();
    }
    int excl = t ? s[t - 1] : 0;
    if (t < NB) { bbase[t] = excl; bcursor[t] = excl; }
    if (t == 0) bbase[NB] = E;
}

__global__ __launch_bounds__(256) void bpart_kernel(const int* __restrict__ src,
                                                    const int* __restrict__ dst,
                                                    int* __restrict__ bcursor,
                                                    unsigned* __restrict__ packed, int E, int NB) {
    __shared__ int cnt[256];
    __shared__ int cur[256];
    const int t = threadIdx.x;
    const int beg = blockIdx.x * 8192;
    const int end = min(beg + 8192, E);
    if (t < NB) cnt[t] = 0;
    __syncthreads();
    for (int e = beg + t; e < end; e += 256) atomicAdd(&cnt[dst[e] >> BSHIFT], 1);
    __syncthreads();
    if (t < NB && cnt[t]) cur[t] = atomicAdd(&bcursor[t], cnt[t]);
    __syncthreads();
    for (int e = beg + t; e < end; e += 256) {
        int d = dst[e];
        int b = d >> BSHIFT;
        int pos = atomicAdd(&cur[b], 1);
        packed[pos] = (unsigned)src[e] | ((unsigned)(d & ((1 << BSHIFT) - 1)) << 16);
    }
}

__global__ __launch_bounds__(256) void bbuild_kernel(const int* __restrict__ bbase,
                                                     const unsigned* __restrict__ packed,
                                                     int* __restrict__ col,
                                                     int* __restrict__ rowstart,
                                                     float* __restrict__ dinv, int N, int E) {
    __shared__ int ncnt[256];
    __shared__ int s[256];
    __shared__ int ncur[256];
    const int b = blockIdx.x;
    const int t = threadIdx.x;
    const int beg = bbase[b], end = bbase[b + 1];
    const int node0 = b << BSHIFT;
    const int nInB = min(256, N - node0);
    ncnt[t] = 0;
    __syncthreads();
    for (int e = beg + t; e < end; e += 256) atomicAdd(&ncnt[packed[e] >> 16], 1);
    __syncthreads();
    s[t] = ncnt[t];
    __syncthreads();
    for (int off = 1; off < 256; off <<= 1) {
        int v = (t >= off) ? s[t - off] : 0;
        __syncthreads();
        s[t] += v;
        __syncthreads();
    }
    int excl = t ? s[t - 1] : 0;
    if (t < nInB) {
        rowstart[node0 + t] = beg + excl;
        dinv[node0 + t] = rsqrtf((float)ncnt[t] + 1.0f);
    }
    ncur[t] = beg + excl;
    __syncthreads();
    for (int e = beg + t; e < end; e += 256) {
        unsigned p = packed[e];
        int pos = atomicAdd(&ncur[p >> 16], 1);
        col[pos] = (int)(p & 0xFFFFu);
    }
    if (b == 0 && t == 0) rowstart[N] = E;
}

// ---------------- CSR gather (bf16 in, bf16/f32 out, 8-deep ILP) ------------
// agg[d,:] = relu(dinv[d]*(hws[d,:] + sum_s hws[s,:]) + bias)
template <int F, bool OBF>
__global__ __launch_bounds__(256) void gather_bf_kernel(const int* __restrict__ rowstart,
                                                        const int* __restrict__ col,
                                                        const float* __restrict__ dinv,
                                                        const ushort_t* __restrict__ hws,
                                                        const float* __restrict__ bias,
                                                        float* __restrict__ agg,
                                                        ushort_t* __restrict__ aggb, int N) {
    const int wave = threadIdx.x >> 6;
    const int lane = threadIdx.x & 63;
    const int d = blockIdx.x * 4 + wave;
    if (d >= N) return;
    const int beg = rowstart[d], end = rowstart[d + 1];
    const float dd = dinv[d];
    if (F == 128) {
        const unsigned* base = (const unsigned*)hws;   // 2 bf16 per uint; row = 64 uints
        unsigned sv = base[(size_t)d * 64 + lane];
        float ax = __uint_as_float(sv << 16);
        float ay = __uint_as_float(sv & 0xFFFF0000u);
        for (int e0 = beg; e0 < end; e0 += 64) {
            int nid = (e0 + lane < end) ? col[e0 + lane] : 0;
            int cnt = min(64, end - e0);
            int j = 0;
            for (; j + 8 <= cnt; j += 8) {
                unsigned u[8];
#pragma unroll
                for (int q = 0; q < 8; ++q) {
                    int s = __shfl(nid, j + q);
                    u[q] = base[(size_t)s * 64 + lane];
                }
#pragma unroll
                for (int q = 0; q < 8; ++q) {
                    ax += __uint_as_float(u[q] << 16);
                    ay += __uint_as_float(u[q] & 0xFFFF0000u);
                }
            }
            for (; j < cnt; ++j) {
                int s = __shfl(nid, j);
                unsigned uu = base[(size_t)s * 64 + lane];
                ax += __uint_as_float(uu << 16);
                ay += __uint_as_float(uu & 0xFFFF0000u);
            }
        }
        float2 b = ((const float2*)bias)[lane];
        float rx = fmaxf(ax * dd + b.x, 0.f);
        float ry = fmaxf(ay * dd + b.y, 0.f);
        if constexpr (OBF) {
            unsigned pk = ((unsigned)f2bf(ry) << 16) | (unsigned)f2bf(rx);
            ((unsigned*)aggb)[(size_t)d * 64 + lane] = pk;
        } else {
            float2 r; r.x = rx; r.y = ry;
            ((float2*)(agg + (size_t)d * 128))[lane] = r;
        }
    } else {  // F == 64: one bf16 per lane
        float acc = __uint_as_float((unsigned)hws[(size_t)d * 64 + lane] << 16);
        for (int e0 = beg; e0 < end; e0 += 64) {
            int nid = (e0 + lane < end) ? col[e0 + lane] : 0;
            int cnt = min(64, end - e0);
            int j = 0;
            for (; j + 8 <= cnt; j += 8) {
                ushort_t u[8];
#pragma unroll
                for (int q = 0; q < 8; ++q) {
                    int s = __shfl(nid, j + q);
                    u[q] = hws[(size_t)s * 64 + lane];
                }
#pragma unroll
                for (int q = 0; q < 8; ++q) acc += __uint_as_float((unsigned)u[q] << 16);
            }
            for (; j < cnt; ++j) {
                int s = __shfl(nid, j);
                acc += __uint_as_float((unsigned)hws[(size_t)s * 64 + lane] << 16);
            }
        }
        acc = fmaxf(acc * dd + bias[lane], 0.f);
        if constexpr (OBF) aggb[(size_t)d * 64 + lane] = f2bf(acc);
        else               agg[(size_t)d * 64 + lane] = acc;
    }
}

// ---------------- edge decode -----------------------------------------------
__global__ __launch_bounds__(256) void decode_kernel(const float* __restrict__ emb1,
                                                     const int* __restrict__ eli,
                                                     const float* __restrict__ Wpost,
                                                     const float* __restrict__ bpost,
                                                     float* __restrict__ pred, int L) {
    const int wave = threadIdx.x >> 6;
    const int lane = threadIdx.x & 63;
    const int l = blockIdx.x * 4 + wave;
    if (l >= L) return;
    int s = eli[l];
    int d = eli[L + l];
    float w = Wpost[lane * 2] + Wpost[lane * 2 + 1];
    float p = emb1[(size_t)s * 64 + lane] * emb1[(size_t)d * 64 + lane] * w;
#pragma unroll
    for (int off = 32; off; off >>= 1) p += __shfl_down(p, off);
    if (lane == 0) pred[l] = p + bpost[0] + bpost[1];
}

// ---------------------------------------------------------------------------
extern "C" void kernel_launch(void* const* d_in, const int* in_sizes, int n_in,
                              void* d_out, int out_size, void* d_ws, size_t ws_size,
                              hipStream_t stream) {
    const float* x     = (const float*)d_in[0];
    const float* prev0 = (const float*)d_in[1];
    const float* prev1 = (const float*)d_in[2];
    const float* Wpre1 = (const float*)d_in[3];
    const float* bpre1 = (const float*)d_in[4];
    const float* Wpre2 = (const float*)d_in[5];
    const float* bpre2 = (const float*)d_in[6];
    const float* Wc1   = (const float*)d_in[7];
    const float* bc1   = (const float*)d_in[8];
    const float* Wc2   = (const float*)d_in[9];
    const float* bc2   = (const float*)d_in[10];
    const float* Wm1   = (const float*)d_in[11];
    const float* bm1   = (const float*)d_in[12];
    const float* Wm2   = (const float*)d_in[13];
    const float* bm2   = (const float*)d_in[14];
    const float* Wpost = (const float*)d_in[15];
    const float* bpost = (const float*)d_in[16];
    const int* edge_index = (const int*)d_in[17];
    const int* eli        = (const int*)d_in[18];

    const int N = in_sizes[0] / 256;   // 50000  (must be <= 65536 for packing)
    const int E = in_sizes[17] / 2;    // 1.6M
    const int L = in_sizes[18] / 2;    // 200K
    const int NB = (N + 255) >> BSHIFT;

    const int* src = edge_index;
    const int* dst = edge_index + E;

    float* out  = (float*)d_out;
    float* pred = out;                        // [L]
    float* emb0 = out + L;                    // [N,128]
    float* emb1 = out + L + (size_t)N * 128;  // [N,64]

    // ---- workspace layout (float slots) ----
    // [0,128N)    : h1h [N,256]us (G1->G2)
    //               then hws1b [N,128]us [0,64N) (G3->gather1)
    //               then agg1b [N,128]us [64N,128N) (gather1->G5)
    //               then hws2b [N,64]us [0,32N) (G6->gather2)
    //               then agg2b [N,64]us [32N,64N) (gather2->G8)
    // [128N,160N) : h2b [N,128]us (G2->G3)
    // [160N,...)  : packed[E] (build only), col[E], rowstart, dinv, buckets, wb
    float* ws = (float*)d_ws;
    ushort_t* h1h   = (ushort_t*)ws;
    ushort_t* hws1b = (ushort_t*)ws;
    ushort_t* hws2b = (ushort_t*)ws;
    ushort_t* agg1b = (ushort_t*)(ws + (size_t)64 * N);
    ushort_t* agg2b = (ushort_t*)(ws + (size_t)32 * N);
    ushort_t* h2b   = (ushort_t*)(ws + (size_t)128 * N);

    size_t o = (size_t)160 * N;
    unsigned* packed = (unsigned*)(ws + o); o += ((size_t)E + 3) & ~(size_t)3;
    int* col = (int*)(ws + o);              o += ((size_t)E + 3) & ~(size_t)3;
    int* rowstart = (int*)(ws + o);         o += ((size_t)N + 4) & ~(size_t)3;
    float* dinv = ws + o;                   o += ((size_t)N + 3) & ~(size_t)3;
    int* bbase = (int*)(ws + o);            o += 260;
    int* bcursor = (int*)(ws + o);          o += 260;
    int* bcount = (int*)(ws + o);           o += 260;
    ushort_t* wb = (ushort_t*)(ws + o);     // 327680 ushorts (16B-aligned)

    // weight hi/lo offsets (ushorts) within wb
    ushort_t* wpre1h = wb + 0;       ushort_t* wpre1l = wb + 65536;
    ushort_t* wpre2h = wb + 131072;  ushort_t* wpre2l = wb + 163840;
    ushort_t* wc1h   = wb + 196608;  ushort_t* wc1l   = wb + 212992;
    ushort_t* wm1h   = wb + 229376;  ushort_t* wm1l   = wb + 262144;
    ushort_t* wc2h   = wb + 294912;  ushort_t* wc2l   = wb + 303104;
    ushort_t* wm2h   = wb + 311296;  ushort_t* wm2l   = wb + 319488;

    // 0) bucketed CSR build + dinv
    hipMemsetAsync(bcount, 0, (size_t)NB * sizeof(int), stream);
    bcount_kernel<<<1024, 256, 0, stream>>>(dst, bcount, E, NB);
    bscan_kernel<<<1, 256, 0, stream>>>(bcount, bbase, bcursor, NB, E);
    bpart_kernel<<<(E + 8191) / 8192, 256, 0, stream>>>(src, dst, bcursor, packed, E, NB);
    bbuild_kernel<<<NB, 256, 0, stream>>>(bbase, packed, col, rowstart, dinv, N, E);

    // 0b) weights: transpose + hi/lo split
    WAll wa;
    wa.d[0] = {Wpre1, wpre1h, wpre1l, 256, 256};
    wa.d[1] = {Wpre2, wpre2h, wpre2l, 256, 128};
    wa.d[2] = {Wc1,   wc1h,   wc1l,   128, 128};
    wa.d[3] = {Wm1,   wm1h,   wm1l,   256, 128};
    wa.d[4] = {Wc2,   wc2h,   wc2l,   128, 64};
    wa.d[5] = {Wm2,   wm2h,   wm2l,   128, 64};
    wtcvt_kernel<<<dim3(256, 6), 256, 0, stream>>>(wa);

    const int gy = (N + 63) / 64;   // 782

    // 1) h1 = bf16(relu(x@Wpre1+b))                    [N,256]
    gemm_mfma<4, true, false, false, false, 2><<<dim3(2, gy), 256, 0, stream>>>(
        x, nullptr, 256, nullptr, 0, wpre1h, wpre1l, bpre1, nullptr,
        nullptr, h1h, N, 256);
    // 2) h2 = bf16(relu(h1@Wpre2+b))                   [N,128]
    gemm_mfma<4, true, false, false, true, 2><<<dim3(1, gy), 256, 0, stream>>>(
        nullptr, h1h, 256, nullptr, 0, wpre2h, wpre2l, bpre2, nullptr,
        nullptr, h2b, N, 128);
    // 3) hws1 = bf16((h2@Wc1)*dinv[row])               [N,128]  (h1 dead)
    gemm_mfma<4, false, true, false, true, 2><<<dim3(1, gy), 256, 0, stream>>>(
        nullptr, h2b, 128, nullptr, 0, wc1h, wc1l, nullptr, dinv,
        nullptr, hws1b, N, 128);
    // 4) agg1 = bf16(relu(dinv*(hws1[d]+sum hws1[s])+bc1))  (h2 dead after this)
    gather_bf_kernel<128, true><<<(N + 3) / 4, 256, 0, stream>>>(
        rowstart, col, dinv, hws1b, bc1, nullptr, agg1b, N);
    // 5) emb0 = [agg1,prev0]@Wm1+bm1  (bf16 A1 + fp32 A2 concat GEMM)
    gemm_mfma<4, false, false, true, true, 0><<<dim3(1, gy), 256, 0, stream>>>(
        nullptr, agg1b, 128, prev0, 128, wm1h, wm1l, bm1, nullptr,
        emb0, nullptr, N, 128);
    // 6) hws2 = bf16((emb0@Wc2)*dinv[row])             [N,64]
    gemm_mfma<2, false, true, false, false, 2><<<dim3(1, gy), 256, 0, stream>>>(
        emb0, nullptr, 128, nullptr, 0, wc2h, wc2l, nullptr, dinv,
        nullptr, hws2b, N, 64);
    // 7) agg2 = bf16(relu(dinv*(hws2[d]+sum hws2[s])+bc2))
    gather_bf_kernel<64, true><<<(N + 3) / 4, 256, 0, stream>>>(
        rowstart, col, dinv, hws2b, bc2, nullptr, agg2b, N);
    // 8) emb1 = [agg2,prev1]@Wm2+bm2  (bf16 A1 + fp32 A2)
    gemm_mfma<2, false, false, true, true, 0><<<dim3(1, gy), 256, 0, stream>>>(
        nullptr, agg2b, 64, prev1, 64, wm2h, wm2l, bm2, nullptr,
        emb1, nullptr, N, 64);
    // 9) decode
    decode_kernel<<<(L + 3) / 4, 256, 0, stream>>>(emb1, eli, Wpost, bpost, pred, L);
}

// Round 9
// 418.551 us; speedup vs baseline: 1.0218x; 1.0218x over previous
//
#include <hip/hip_runtime.h>
#include <hip/hip_bf16.h>

// ---------------------------------------------------------------------------
// ROLAND-style GNN forward. Round 8: weight-stationary streaming GEMM --
// W panel (hi/lo bf16, XOR-swizzled) resident in LDS, ONE barrier per block,
// waves independently stream 32-row A tiles with full K unroll (no staging
// pipeline, no per-tile barriers). bf16 decode operand. Bucketed CSR build;
// bf16 CSR gather with 8-deep ILP.
// ---------------------------------------------------------------------------

typedef unsigned short ushort_t;
typedef __attribute__((ext_vector_type(8))) short s8v;   // 8 bf16 (4 VGPRs)
typedef __attribute__((ext_vector_type(4))) float f4;    // MFMA accumulator

#define BSHIFT 8                       // nodes per bucket = 256 (N<=65536)

__device__ __forceinline__ void bsplit(float v, ushort_t& hi, ushort_t& lo) {
    unsigned u = __float_as_uint(v);
    unsigned rh = u + 0x7FFFu + ((u >> 16) & 1u);
    hi = (ushort_t)(rh >> 16);
    float fh = __uint_as_float((unsigned)hi << 16);
    float d = v - fh;
    unsigned u2 = __float_as_uint(d);
    unsigned rl = u2 + 0x7FFFu + ((u2 >> 16) & 1u);
    lo = (ushort_t)(rl >> 16);
}

__device__ __forceinline__ ushort_t f2bf(float v) {
    unsigned u = __float_as_uint(v);
    return (ushort_t)((u + 0x7FFFu + ((u >> 16) & 1u)) >> 16);
}

__device__ __forceinline__ s8v cvt8(f4 v0, f4 v1) {
    ushort_t hb[8];
    hb[0] = f2bf(v0.x); hb[1] = f2bf(v0.y); hb[2] = f2bf(v0.z); hb[3] = f2bf(v0.w);
    hb[4] = f2bf(v1.x); hb[5] = f2bf(v1.y); hb[6] = f2bf(v1.z); hb[7] = f2bf(v1.w);
    return *(s8v*)hb;
}

// ---------------- weight-stationary streaming MFMA GEMM ---------------------
// C[M,Nout] = epilogue( A[M,K1T] (++ A2[M,KWT-K1T]) @ W[KWT,Nout] )
// Block: 256 thr = 4 waves; 64-col W panel (hi+lo) in LDS, loaded once.
// Each wave grid-strides over 32-row A tiles; K fully unrolled (KWT template).
// ABF: A1 is bf16. OUTMODE: 0 = fp32, 2 = bf16, 3 = fp32 + bf16 copy.
template <int KWT, int K1T, bool RELU, bool SCALE, bool DUAL, bool ABF, int OUTMODE>
__global__ __launch_bounds__(256) void gemm_ws(
    const float* __restrict__ A1f, const ushort_t* __restrict__ A1h,
    const float* __restrict__ A2f,
    const ushort_t* __restrict__ Wth, const ushort_t* __restrict__ Wtl,
    const float* __restrict__ bias, const float* __restrict__ rowscale,
    float* __restrict__ Cf, ushort_t* __restrict__ Ch,
    int M, int Nout)
{
    constexpr int NT = 4;              // 4 x 16 = 64 cols per block
    constexpr int NTIL = KWT / 64;     // k-tiles
    constexpr int NCH = KWT / 8;       // 16B chunks per W row
    __shared__ ushort_t wh[64 * KWT];
    __shared__ ushort_t wl[64 * KWT];

    const int tid  = threadIdx.x;
    const int lane = tid & 63;
    const int w    = tid >> 6;
    const int bn   = blockIdx.x * 64;

    // ---- cooperative W panel load (rows bn..bn+63), chunk-XOR swizzle ----
#pragma unroll
    for (int i = 0; i < (64 * NCH) / 256; ++i) {
        int idx = tid + i * 256;
        int r = idx / NCH, c = idx % NCH;
        int pc = c ^ (r & 7);
        *(s8v*)&wh[r * KWT + pc * 8] = *(const s8v*)&Wth[(size_t)(bn + r) * KWT + c * 8];
        *(s8v*)&wl[r * KWT + pc * 8] = *(const s8v*)&Wtl[(size_t)(bn + r) * KWT + c * 8];
    }
    __syncthreads();   // the ONLY barrier

    const int ntiles = (M + 31) >> 5;
    const int tstep  = gridDim.y * 4;

    for (int tile = blockIdx.y * 4 + w; tile < ntiles; tile += tstep) {
        const int rbase = tile * 32;

        // ---- load ALL A fragments for this tile into registers ----
        s8v af[NTIL][4];   // [t][mi*2+ks]
#pragma unroll
        for (int t = 0; t < NTIL; ++t) {
#pragma unroll
            for (int mi = 0; mi < 2; ++mi) {
                const int row = min(rbase + mi * 16 + (lane & 15), M - 1);
#pragma unroll
                for (int ks = 0; ks < 2; ++ks) {
                    const int k = t * 64 + ks * 32 + (lane >> 4) * 8;
                    if (DUAL && t * 64 >= K1T) {
                        const float* sp = &A2f[(size_t)row * (KWT - K1T) + (k - K1T)];
                        af[t][mi * 2 + ks] = cvt8(*(const f4*)sp, *(const f4*)(sp + 4));
                    } else if (ABF) {
                        af[t][mi * 2 + ks] = *(const s8v*)&A1h[(size_t)row * K1T + k];
                    } else {
                        const float* sp = &A1f[(size_t)row * K1T + k];
                        af[t][mi * 2 + ks] = cvt8(*(const f4*)sp, *(const f4*)(sp + 4));
                    }
                }
            }
        }

        // ---- MFMA: K fully unrolled, weights from LDS ----
        f4 acc[2][NT];
        const f4 zero = {0.f, 0.f, 0.f, 0.f};
#pragma unroll
        for (int mi = 0; mi < 2; ++mi)
#pragma unroll
            for (int ni = 0; ni < NT; ++ni) acc[mi][ni] = zero;

#pragma unroll
        for (int t = 0; t < NTIL; ++t) {
#pragma unroll
            for (int ks = 0; ks < 2; ++ks) {
                const int cch = t * 8 + ks * 4 + (lane >> 4);
                s8v bh[NT], bl[NT];
#pragma unroll
                for (int ni = 0; ni < NT; ++ni) {
                    const int r = ni * 16 + (lane & 15);
                    const int pc = cch ^ (r & 7);
                    bh[ni] = *(const s8v*)&wh[r * KWT + pc * 8];
                    bl[ni] = *(const s8v*)&wl[r * KWT + pc * 8];
                }
#pragma unroll
                for (int mi = 0; mi < 2; ++mi) {
                    const s8v ah = af[t][mi * 2 + ks];
#pragma unroll
                    for (int ni = 0; ni < NT; ++ni) {
                        acc[mi][ni] = __builtin_amdgcn_mfma_f32_16x16x32_bf16(ah, bh[ni], acc[mi][ni], 0, 0, 0);
                        acc[mi][ni] = __builtin_amdgcn_mfma_f32_16x16x32_bf16(ah, bl[ni], acc[mi][ni], 0, 0, 0);
                    }
                }
            }
        }

        // ---- epilogue: C/D layout col=lane&15, row=(lane>>4)*4+reg ----
#pragma unroll
        for (int mi = 0; mi < 2; ++mi) {
#pragma unroll
            for (int reg = 0; reg < 4; ++reg) {
                const int row = rbase + mi * 16 + (lane >> 4) * 4 + reg;
                if (row >= M) continue;
                const float rs = SCALE ? rowscale[row] : 1.f;
#pragma unroll
                for (int ni = 0; ni < NT; ++ni) {
                    const int col = bn + ni * 16 + (lane & 15);
                    float v = acc[mi][ni][reg];
                    if (SCALE) v *= rs;
                    if (bias) v += bias[col];
                    if (RELU) v = fmaxf(v, 0.f);
                    if constexpr (OUTMODE == 2) {
                        Ch[(size_t)row * Nout + col] = f2bf(v);
                    } else if constexpr (OUTMODE == 3) {
                        Cf[(size_t)row * Nout + col] = v;
                        Ch[(size_t)row * Nout + col] = f2bf(v);
                    } else {
                        Cf[(size_t)row * Nout + col] = v;
                    }
                }
            }
        }
    }
}

// ---------------- weight transpose + split ---------------------------------
struct WDesc { const float* W; ushort_t* h; ushort_t* l; int K; int No; };
struct WAll { WDesc d[6]; };

__global__ void wtcvt_kernel(WAll wa) {
    WDesc d = wa.d[blockIdx.y];
    int e = blockIdx.x * blockDim.x + threadIdx.x;
    if (e >= d.K * d.No) return;
    int k = e / d.No, n = e - k * d.No;
    ushort_t h, l;
    bsplit(d.W[e], h, l);
    d.h[(size_t)n * d.K + k] = h;
    d.l[(size_t)n * d.K + k] = l;
}

// ---------------- bucketed CSR build ----------------------------------------
__global__ __launch_bounds__(256) void bcount_kernel(const int* __restrict__ dst,
                                                     int* __restrict__ bcount, int E, int NB) {
    __shared__ int cnt[256];
    const int t = threadIdx.x;
    if (t < NB) cnt[t] = 0;
    __syncthreads();
    for (int e = blockIdx.x * 256 + t; e < E; e += gridDim.x * 256)
        atomicAdd(&cnt[dst[e] >> BSHIFT], 1);
    __syncthreads();
    if (t < NB && cnt[t]) atomicAdd(&bcount[t], cnt[t]);
}

__global__ __launch_bounds__(256) void bscan_kernel(const int* __restrict__ bcount,
                                                    int* __restrict__ bbase,
                                                    int* __restrict__ bcursor, int NB, int E) {
    __shared__ int s[256];
    const int t = threadIdx.x;
    s[t] = (t < NB) ? bcount[t] : 0;
    __syncthreads();
    for (int off = 1; off < 256; off <<= 1) {
        int v = (t >= off) ? s[t - off] : 0;
        __syncthreads();
        s[t] += v;
        __syncthreads();
    }
    int excl = t ? s[t - 1] : 0;
    if (t < NB) { bbase[t] = excl; bcursor[t] = excl; }
    if (t == 0) bbase[NB] = E;
}

__global__ __launch_bounds__(256) void bpart_kernel(const int* __restrict__ src,
                                                    const int* __restrict__ dst,
                                                    int* __restrict__ bcursor,
                                                    unsigned* __restrict__ packed, int E, int NB) {
    __shared__ int cnt[256];
    __shared__ int cur[256];
    const int t = threadIdx.x;
    const int beg = blockIdx.x * 8192;
    const int end = min(beg + 8192, E);
    if (t < NB) cnt[t] = 0;
    __syncthreads();
    for (int e = beg + t; e < end; e += 256) atomicAdd(&cnt[dst[e] >> BSHIFT], 1);
    __syncthreads();
    if (t < NB && cnt[t]) cur[t] = atomicAdd(&bcursor[t], cnt[t]);
    __syncthreads();
    for (int e = beg + t; e < end; e += 256) {
        int d = dst[e];
        int b = d >> BSHIFT;
        int pos = atomicAdd(&cur[b], 1);
        packed[pos] = (unsigned)src[e] | ((unsigned)(d & ((1 << BSHIFT) - 1)) << 16);
    }
}

__global__ __launch_bounds__(256) void bbuild_kernel(const int* __restrict__ bbase,
                                                     const unsigned* __restrict__ packed,
                                                     int* __restrict__ col,
                                                     int* __restrict__ rowstart,
                                                     float* __restrict__ dinv, int N, int E) {
    __shared__ int ncnt[256];
    __shared__ int s[256];
    __shared__ int ncur[256];
    const int b = blockIdx.x;
    const int t = threadIdx.x;
    const int beg = bbase[b], end = bbase[b + 1];
    const int node0 = b << BSHIFT;
    const int nInB = min(256, N - node0);
    ncnt[t] = 0;
    __syncthreads();
    for (int e = beg + t; e < end; e += 256) atomicAdd(&ncnt[packed[e] >> 16], 1);
    __syncthreads();
    s[t] = ncnt[t];
    __syncthreads();
    for (int off = 1; off < 256; off <<= 1) {
        int v = (t >= off) ? s[t - off] : 0;
        __syncthreads();
        s[t] += v;
        __syncthreads();
    }
    int excl = t ? s[t - 1] : 0;
    if (t < nInB) {
        rowstart[node0 + t] = beg + excl;
        dinv[node0 + t] = rsqrtf((float)ncnt[t] + 1.0f);
    }
    ncur[t] = beg + excl;
    __syncthreads();
    for (int e = beg + t; e < end; e += 256) {
        unsigned p = packed[e];
        int pos = atomicAdd(&ncur[p >> 16], 1);
        col[pos] = (int)(p & 0xFFFFu);
    }
    if (b == 0 && t == 0) rowstart[N] = E;
}

// ---------------- CSR gather (bf16 in, bf16 out, 8-deep ILP) ----------------
template <int F>
__global__ __launch_bounds__(256) void gather_bf_kernel(const int* __restrict__ rowstart,
                                                        const int* __restrict__ col,
                                                        const float* __restrict__ dinv,
                                                        const ushort_t* __restrict__ hws,
                                                        const float* __restrict__ bias,
                                                        ushort_t* __restrict__ aggb, int N) {
    const int wave = threadIdx.x >> 6;
    const int lane = threadIdx.x & 63;
    const int d = blockIdx.x * 4 + wave;
    if (d >= N) return;
    const int beg = rowstart[d], end = rowstart[d + 1];
    const float dd = dinv[d];
    if (F == 128) {
        const unsigned* base = (const unsigned*)hws;   // 2 bf16 per uint
        unsigned sv = base[(size_t)d * 64 + lane];
        float ax = __uint_as_float(sv << 16);
        float ay = __uint_as_float(sv & 0xFFFF0000u);
        for (int e0 = beg; e0 < end; e0 += 64) {
            int nid = (e0 + lane < end) ? col[e0 + lane] : 0;
            int cnt = min(64, end - e0);
            int j = 0;
            for (; j + 8 <= cnt; j += 8) {
                unsigned u[8];
#pragma unroll
                for (int q = 0; q < 8; ++q) {
                    int s = __shfl(nid, j + q);
                    u[q] = base[(size_t)s * 64 + lane];
                }
#pragma unroll
                for (int q = 0; q < 8; ++q) {
                    ax += __uint_as_float(u[q] << 16);
                    ay += __uint_as_float(u[q] & 0xFFFF0000u);
                }
            }
            for (; j < cnt; ++j) {
                int s = __shfl(nid, j);
                unsigned uu = base[(size_t)s * 64 + lane];
                ax += __uint_as_float(uu << 16);
                ay += __uint_as_float(uu & 0xFFFF0000u);
            }
        }
        float2 b = ((const float2*)bias)[lane];
        float rx = fmaxf(ax * dd + b.x, 0.f);
        float ry = fmaxf(ay * dd + b.y, 0.f);
        unsigned pk = ((unsigned)f2bf(ry) << 16) | (unsigned)f2bf(rx);
        ((unsigned*)aggb)[(size_t)d * 64 + lane] = pk;
    } else {  // F == 64
        float acc = __uint_as_float((unsigned)hws[(size_t)d * 64 + lane] << 16);
        for (int e0 = beg; e0 < end; e0 += 64) {
            int nid = (e0 + lane < end) ? col[e0 + lane] : 0;
            int cnt = min(64, end - e0);
            int j = 0;
            for (; j + 8 <= cnt; j += 8) {
                ushort_t u[8];
#pragma unroll
                for (int q = 0; q < 8; ++q) {
                    int s = __shfl(nid, j + q);
                    u[q] = hws[(size_t)s * 64 + lane];
                }
#pragma unroll
                for (int q = 0; q < 8; ++q) acc += __uint_as_float((unsigned)u[q] << 16);
            }
            for (; j < cnt; ++j) {
                int s = __shfl(nid, j);
                acc += __uint_as_float((unsigned)hws[(size_t)s * 64 + lane] << 16);
            }
        }
        acc = fmaxf(acc * dd + bias[lane], 0.f);
        aggb[(size_t)d * 64 + lane] = f2bf(acc);
    }
}

// ---------------- edge decode (bf16 emb1 copy) ------------------------------
__global__ __launch_bounds__(256) void decode_kernel(const ushort_t* __restrict__ emb1b,
                                                     const int* __restrict__ eli,
                                                     const float* __restrict__ Wpost,
                                                     const float* __restrict__ bpost,
                                                     float* __restrict__ pred, int L) {
    const int wave = threadIdx.x >> 6;
    const int lane = threadIdx.x & 63;
    const int l = blockIdx.x * 4 + wave;
    if (l >= L) return;
    int s = eli[l];
    int d = eli[L + l];
    float w = Wpost[lane * 2] + Wpost[lane * 2 + 1];
    float a = __uint_as_float((unsigned)emb1b[(size_t)s * 64 + lane] << 16);
    float b = __uint_as_float((unsigned)emb1b[(size_t)d * 64 + lane] << 16);
    float p = a * b * w;
#pragma unroll
    for (int off = 32; off; off >>= 1) p += __shfl_down(p, off);
    if (lane == 0) pred[l] = p + bpost[0] + bpost[1];
}

// ---------------------------------------------------------------------------
extern "C" void kernel_launch(void* const* d_in, const int* in_sizes, int n_in,
                              void* d_out, int out_size, void* d_ws, size_t ws_size,
                              hipStream_t stream) {
    const float* x     = (const float*)d_in[0];
    const float* prev0 = (const float*)d_in[1];
    const float* prev1 = (const float*)d_in[2];
    const float* Wpre1 = (const float*)d_in[3];
    const float* bpre1 = (const float*)d_in[4];
    const float* Wpre2 = (const float*)d_in[5];
    const float* bpre2 = (const float*)d_in[6];
    const float* Wc1   = (const float*)d_in[7];
    const float* bc1   = (const float*)d_in[8];
    const float* Wc2   = (const float*)d_in[9];
    const float* bc2   = (const float*)d_in[10];
    const float* Wm1   = (const float*)d_in[11];
    const float* bm1   = (const float*)d_in[12];
    const float* Wm2   = (const float*)d_in[13];
    const float* bm2   = (const float*)d_in[14];
    const float* Wpost = (const float*)d_in[15];
    const float* bpost = (const float*)d_in[16];
    const int* edge_index = (const int*)d_in[17];
    const int* eli        = (const int*)d_in[18];

    const int N = in_sizes[0] / 256;   // 50000  (must be <= 65536 for packing)
    const int E = in_sizes[17] / 2;    // 1.6M
    const int L = in_sizes[18] / 2;    // 200K
    const int NB = (N + 255) >> BSHIFT;

    const int* src = edge_index;
    const int* dst = edge_index + E;

    float* out  = (float*)d_out;
    float* pred = out;                        // [L]
    float* emb0 = out + L;                    // [N,128]
    float* emb1 = out + L + (size_t)N * 128;  // [N,64]

    // ---- workspace layout (float slots) ----
    // [0,128N)    : h1h [N,256]us (G1->G2)
    //               then hws1b [N,128]us [0,64N) / agg1b [64N,128N)
    //               then hws2b [N,64]us [0,32N) / agg2b [32N,64N)
    //               then emb1b [N,64]us [64N,96N) (G8->decode; agg1b dead)
    // [128N,160N) : h2b [N,128]us (G2->G3)
    // [160N,...)  : packed[E] (build only), col[E], rowstart, dinv, buckets, wb
    float* ws = (float*)d_ws;
    ushort_t* h1h   = (ushort_t*)ws;
    ushort_t* hws1b = (ushort_t*)ws;
    ushort_t* hws2b = (ushort_t*)ws;
    ushort_t* agg1b = (ushort_t*)(ws + (size_t)64 * N);
    ushort_t* agg2b = (ushort_t*)(ws + (size_t)32 * N);
    ushort_t* emb1b = (ushort_t*)(ws + (size_t)64 * N);
    ushort_t* h2b   = (ushort_t*)(ws + (size_t)128 * N);

    size_t o = (size_t)160 * N;
    unsigned* packed = (unsigned*)(ws + o); o += ((size_t)E + 3) & ~(size_t)3;
    int* col = (int*)(ws + o);              o += ((size_t)E + 3) & ~(size_t)3;
    int* rowstart = (int*)(ws + o);         o += ((size_t)N + 4) & ~(size_t)3;
    float* dinv = ws + o;                   o += ((size_t)N + 3) & ~(size_t)3;
    int* bbase = (int*)(ws + o);            o += 260;
    int* bcursor = (int*)(ws + o);          o += 260;
    int* bcount = (int*)(ws + o);           o += 260;
    ushort_t* wb = (ushort_t*)(ws + o);     // 327680 ushorts (16B-aligned)

    ushort_t* wpre1h = wb + 0;       ushort_t* wpre1l = wb + 65536;
    ushort_t* wpre2h = wb + 131072;  ushort_t* wpre2l = wb + 163840;
    ushort_t* wc1h   = wb + 196608;  ushort_t* wc1l   = wb + 212992;
    ushort_t* wm1h   = wb + 229376;  ushort_t* wm1l   = wb + 262144;
    ushort_t* wc2h   = wb + 294912;  ushort_t* wc2l   = wb + 303104;
    ushort_t* wm2h   = wb + 311296;  ushort_t* wm2l   = wb + 319488;

    // 0) bucketed CSR build + dinv
    hipMemsetAsync(bcount, 0, (size_t)NB * sizeof(int), stream);
    bcount_kernel<<<1024, 256, 0, stream>>>(dst, bcount, E, NB);
    bscan_kernel<<<1, 256, 0, stream>>>(bcount, bbase, bcursor, NB, E);
    bpart_kernel<<<(E + 8191) / 8192, 256, 0, stream>>>(src, dst, bcursor, packed, E, NB);
    bbuild_kernel<<<NB, 256, 0, stream>>>(bbase, packed, col, rowstart, dinv, N, E);

    // 0b) weights: transpose + hi/lo split
    WAll wa;
    wa.d[0] = {Wpre1, wpre1h, wpre1l, 256, 256};
    wa.d[1] = {Wpre2, wpre2h, wpre2l, 256, 128};
    wa.d[2] = {Wc1,   wc1h,   wc1l,   128, 128};
    wa.d[3] = {Wm1,   wm1h,   wm1l,   256, 128};
    wa.d[4] = {Wc2,   wc2h,   wc2l,   128, 64};
    wa.d[5] = {Wm2,   wm2h,   wm2l,   128, 64};
    wtcvt_kernel<<<dim3(256, 6), 256, 0, stream>>>(wa);

    const int mt = (N + 127) / 128;   // row-tiles/4 = 391

    // 1) h1 = bf16(relu(x@Wpre1+b))           [N,256]   K=256
    gemm_ws<256, 256, true, false, false, false, 2><<<dim3(4, mt < 128 ? mt : 128), 256, 0, stream>>>(
        x, nullptr, nullptr, wpre1h, wpre1l, bpre1, nullptr, nullptr, h1h, N, 256);
    // 2) h2 = bf16(relu(h1@Wpre2+b))          [N,128]   K=256
    gemm_ws<256, 256, true, false, false, true, 2><<<dim3(2, mt < 256 ? mt : 256), 256, 0, stream>>>(
        nullptr, h1h, nullptr, wpre2h, wpre2l, bpre2, nullptr, nullptr, h2b, N, 128);
    // 3) hws1 = bf16((h2@Wc1)*dinv[row])      [N,128]   K=128  (h1 dead)
    gemm_ws<128, 128, false, true, false, true, 2><<<dim3(2, mt), 256, 0, stream>>>(
        nullptr, h2b, nullptr, wc1h, wc1l, nullptr, dinv, nullptr, hws1b, N, 128);
    // 4) agg1 = bf16(relu(dinv*(hws1[d]+sum hws1[s])+bc1))
    gather_bf_kernel<128><<<(N + 3) / 4, 256, 0, stream>>>(rowstart, col, dinv, hws1b, bc1, agg1b, N);
    // 5) emb0 = [agg1,prev0]@Wm1+bm1          [N,128]   K=128+128
    gemm_ws<256, 128, false, false, true, true, 0><<<dim3(2, mt < 256 ? mt : 256), 256, 0, stream>>>(
        nullptr, agg1b, prev0, wm1h, wm1l, bm1, nullptr, emb0, nullptr, N, 128);
    // 6) hws2 = bf16((emb0@Wc2)*dinv[row])    [N,64]    K=128
    gemm_ws<128, 128, false, true, false, false, 2><<<dim3(1, mt), 256, 0, stream>>>(
        emb0, nullptr, nullptr, wc2h, wc2l, nullptr, dinv, nullptr, hws2b, N, 64);
    // 7) agg2 = bf16(relu(dinv*(hws2[d]+sum hws2[s])+bc2))
    gather_bf_kernel<64><<<(N + 3) / 4, 256, 0, stream>>>(rowstart, col, dinv, hws2b, bc2, agg2b, N);
    // 8) emb1 = [agg2,prev1]@Wm2+bm2 (fp32 + bf16 copy)  [N,64]  K=64+64
    gemm_ws<128, 64, false, false, true, true, 3><<<dim3(1, mt), 256, 0, stream>>>(
        nullptr, agg2b, prev1, wm2h, wm2l, bm2, nullptr, emb1, emb1b, N, 64);
    // 9) decode (bf16 emb1 copy, L2-resident)
    decode_kernel<<<(L + 3) / 4, 256, 0, stream>>>(emb1b, eli, Wpost, bpost, pred, L);
}